// Round 1
// baseline (852.741 us; speedup 1.0000x reference)
//
#include <hip/hip_runtime.h>
#include <cstdint>

#define BB 16
#define NN 25200
#define NCLS 80
#define ROW 85
#define MAXDET 300
#define HBINS 2048
#define CAP 2048
#define TARGET 1024
#define CONF_T 0.25f
#define IOU_T 0.45f

// ---------------- workspace layout (bytes) ----------------
// hist : [BB][HBINS] u32            @ 0          (131072)
// thr  : [BB] u32                   @ 131072     (64)
// cnt  : [BB] u32                   @ 131136     (64)
// box  : float4 [BB*NN]             @ 131200     (6451200)   raw xyxy
// score: float  [BB*NN]             @ 6582400    (1612800)   conf or -1
// cls  : u32    [BB*NN]             @ 8195200    (1612800)
// pscr : float  [BB][CAP]           @ 9808000    (131072)
// pidx : u32    [BB][CAP]           @ 9939072    (131072)
// total ~ 10.1 MB
static const size_t OFF_THR  = 131072;
static const size_t OFF_CNT  = 131136;
static const size_t OFF_BOX  = 131200;
static const size_t OFF_SCR  = 6582400;
static const size_t OFF_CLS  = 8195200;
static const size_t OFF_PSC  = 9808000;
static const size_t OFF_PIX  = 9939072;

__global__ __launch_bounds__(256) void k_pre(const float* __restrict__ pred,
                                             float4* __restrict__ boxArr,
                                             float* __restrict__ scoreArr,
                                             unsigned* __restrict__ clsArr,
                                             unsigned* __restrict__ hist) {
    int i = blockIdx.x * 256 + threadIdx.x;
    if (i >= BB * NN) return;
    const float* row = pred + (size_t)i * ROW;
    float cx = row[0], cy = row[1], w = row[2], h = row[3], obj = row[4];
    // conf = max(cls*obj), j = first-occurrence argmax (strict >), matches numpy
    float best = __fmul_rn(row[5], obj);
    int bj = 0;
    for (int c = 1; c < NCLS; ++c) {
        float v = __fmul_rn(row[5 + c], obj);
        if (v > best) { best = v; bj = c; }
    }
    // xywh -> xyxy with no FMA contraction (match numpy rounding)
    float hw = __fmul_rn(w, 0.5f), hh = __fmul_rn(h, 0.5f);
    float4 bx;
    bx.x = __fsub_rn(cx, hw);
    bx.y = __fsub_rn(cy, hh);
    bx.z = __fadd_rn(cx, hw);
    bx.w = __fadd_rn(cy, hh);
    bool valid = (obj > CONF_T) && (best > CONF_T);
    float score = valid ? best : -1.0f;
    boxArr[i] = bx;
    scoreArr[i] = score;
    clsArr[i] = (unsigned)bj;
    if (score > 0.0f) {
        // score in (0.25, 0.9): float bits monotone; 2048 bins
        unsigned key = (__float_as_uint(score) - 0x3E800000u) >> 13;
        if (key > HBINS - 1) key = HBINS - 1;
        int b = i / NN;
        atomicAdd(&hist[b * HBINS + key], 1u);
    }
}

__global__ void k_thr(const unsigned* __restrict__ hist, unsigned* __restrict__ thr) {
    int b = threadIdx.x;
    if (b < BB) {
        unsigned cum = 0;
        int t = 0;
        for (int k = HBINS - 1; k >= 0; --k) {
            cum += hist[b * HBINS + k];
            if (cum >= TARGET) { t = k; break; }
        }
        thr[b] = (unsigned)t;
    }
}

__global__ __launch_bounds__(256) void k_compact(const float* __restrict__ scoreArr,
                                                 const unsigned* __restrict__ thr,
                                                 unsigned* __restrict__ cnt,
                                                 float* __restrict__ pscr,
                                                 unsigned* __restrict__ pidx) {
    int i = blockIdx.x * 256 + threadIdx.x;
    if (i >= BB * NN) return;
    float s = scoreArr[i];
    if (s > 0.0f) {
        int b = i / NN;
        int n = i - b * NN;
        unsigned key = (__float_as_uint(s) - 0x3E800000u) >> 13;
        if (key > HBINS - 1) key = HBINS - 1;
        if (key >= thr[b]) {
            unsigned pos = atomicAdd(&cnt[b], 1u);
            if (pos < CAP) {
                pscr[b * CAP + pos] = s;
                pidx[b * CAP + pos] = (unsigned)n;
            }
        }
    }
}

__global__ __launch_bounds__(256) void k_nms(const float4* __restrict__ boxArr,
                                             const unsigned* __restrict__ clsArr,
                                             const float* __restrict__ logits,
                                             const float* __restrict__ pscrG,
                                             const unsigned* __restrict__ pidxG,
                                             const unsigned* __restrict__ cnt,
                                             float* __restrict__ out) {
    __shared__ float  ps[CAP];
    __shared__ int    pi[CAP];
    __shared__ float4 cbox[CAP];     // class-offset boxes, sorted order
    __shared__ float4 kbox[MAXDET];  // kept offset boxes
    __shared__ int    rowsrc[MAXDET];
    __shared__ float  rowscore[MAXDET];
    __shared__ int    s_kept;

    int b = blockIdx.x;
    int tid = threadIdx.x;
    int c = min((int)cnt[b], CAP);

    // load pairs + sentinel pad
    for (int p = tid; p < CAP; p += 256) {
        if (p < c) { ps[p] = pscrG[b * CAP + p]; pi[p] = (int)pidxG[b * CAP + p]; }
        else       { ps[p] = -1e30f;             pi[p] = 0x7fffffff; }
    }
    __syncthreads();

    // bitonic sort descending by (score, then ascending idx) — exact total order
    for (int k = 2; k <= CAP; k <<= 1) {
        for (int j = k >> 1; j > 0; j >>= 1) {
            for (int i = tid; i < CAP; i += 256) {
                int ixj = i ^ j;
                if (ixj > i) {
                    float s1 = ps[i], s2 = ps[ixj];
                    int i1 = pi[i], i2 = pi[ixj];
                    bool before = (s1 > s2) || ((s1 == s2) && (i1 < i2));
                    bool desc = ((i & k) == 0);
                    bool sw = desc ? !before : before;
                    if (sw) { ps[i] = s2; ps[ixj] = s1; pi[i] = i2; pi[ixj] = i1; }
                }
            }
            __syncthreads();
        }
    }

    // preload offset boxes for sorted candidates (exactly: box + j*4096 on all 4 coords)
    for (int p = tid; p < c; p += 256) {
        int n = pi[p];
        float4 bb = boxArr[(size_t)b * NN + n];
        float off = __fmul_rn((float)clsArr[(size_t)b * NN + n], 4096.0f);
        bb.x = __fadd_rn(bb.x, off);
        bb.y = __fadd_rn(bb.y, off);
        bb.z = __fadd_rn(bb.z, off);
        bb.w = __fadd_rn(bb.w, off);
        cbox[p] = bb;
    }
    __syncthreads();

    // single-wave sequential NMS scan (equivalent to greedy argmax NMS)
    if (tid < 64) {
        int lane = tid;
        int kept = 0;
        for (int p = 0; p < c && kept < MAXDET; ++p) {
            float4 cb = cbox[p];
            float a2 = __fmul_rn(__fsub_rn(cb.z, cb.x), __fsub_rn(cb.w, cb.y));
            bool sup = false;
            for (int k = lane; k < kept; k += 64) {
                float4 kb = kbox[k];
                float ltx = fmaxf(kb.x, cb.x), lty = fmaxf(kb.y, cb.y);
                float rbx = fminf(kb.z, cb.z), rby = fminf(kb.w, cb.w);
                float ww = fmaxf(__fsub_rn(rbx, ltx), 0.0f);
                float hh = fmaxf(__fsub_rn(rby, lty), 0.0f);
                float inter = __fmul_rn(ww, hh);
                float a1 = __fmul_rn(__fsub_rn(kb.z, kb.x), __fsub_rn(kb.w, kb.y));
                float denom = __fadd_rn(__fsub_rn(__fadd_rn(a1, a2), inter), 1e-9f);
                float iou = inter / denom;
                sup = sup || (iou > IOU_T);
            }
            if (__ballot(sup) == 0ULL) {
                if (lane == 0) { kbox[kept] = cb; rowsrc[kept] = pi[p]; rowscore[kept] = ps[p]; }
                kept++;
            }
        }
        if (tid == 0) s_kept = kept;
    }
    __syncthreads();
    int kept = s_kept;

    // outputs (every element written every launch — d_out is poisoned)
    float* dets = out;                                   // [BB][300][6]
    float* lg   = out + (size_t)BB * MAXDET * 6;         // [BB][300][80]
    float* kp   = lg  + (size_t)BB * MAXDET * NCLS;      // [BB][300]

    for (int i = tid; i < MAXDET * 6; i += 256) {
        int t = i / 6, col = i - t * 6;
        float v = 0.0f;
        if (t < kept) {
            int n = rowsrc[t];
            if (col < 4) {
                const float* bp = (const float*)&boxArr[(size_t)b * NN + n];
                v = bp[col];
            } else if (col == 4) {
                v = rowscore[t];
            } else {
                v = (float)clsArr[(size_t)b * NN + n];
            }
        }
        dets[(size_t)b * MAXDET * 6 + i] = v;
    }
    for (int i = tid; i < MAXDET; i += 256) {
        kp[b * MAXDET + i] = (i < kept) ? 1.0f : 0.0f;
    }
    for (int i = tid; i < MAXDET * NCLS; i += 256) {
        int t = i / NCLS, col = i - t * NCLS;
        float v = 0.0f;
        if (t < kept) v = logits[((size_t)b * NN + rowsrc[t]) * NCLS + col];
        lg[(size_t)b * MAXDET * NCLS + i] = v;
    }
}

extern "C" void kernel_launch(void* const* d_in, const int* in_sizes, int n_in,
                              void* d_out, int out_size, void* d_ws, size_t ws_size,
                              hipStream_t stream) {
    const float* pred   = (const float*)d_in[0];
    const float* logits = (const float*)d_in[1];
    float* out = (float*)d_out;
    char* ws = (char*)d_ws;

    unsigned* hist = (unsigned*)ws;
    unsigned* thr  = (unsigned*)(ws + OFF_THR);
    unsigned* cnt  = (unsigned*)(ws + OFF_CNT);
    float4*   box  = (float4*)(ws + OFF_BOX);
    float*    scr  = (float*)(ws + OFF_SCR);
    unsigned* cls  = (unsigned*)(ws + OFF_CLS);
    float*    pscr = (float*)(ws + OFF_PSC);
    unsigned* pidx = (unsigned*)(ws + OFF_PIX);

    hipMemsetAsync(ws, 0, OFF_BOX, stream);  // hist + thr + cnt

    int total = BB * NN;
    int blocks = (total + 255) / 256;
    k_pre<<<blocks, 256, 0, stream>>>(pred, box, scr, cls, hist);
    k_thr<<<1, 64, 0, stream>>>(hist, thr);
    k_compact<<<blocks, 256, 0, stream>>>(scr, thr, cnt, pscr, pidx);
    k_nms<<<BB, 256, 0, stream>>>(box, cls, logits, pscr, pidx, cnt, out);
}

// Round 2
// 494.064 us; speedup vs baseline: 1.7260x; 1.7260x over previous
//
#include <hip/hip_runtime.h>
#include <cstdint>

#define BB 16
#define NN 25200
#define NCLS 80
#define ROW 85
#define MAXDET 300
#define HBINS 2048
#define CAP2 512
#define TGT 448
#define CONF_T 0.25f
#define IOU_T 0.45f

// ---------------- workspace layout (bytes) ----------------
// hist : [BB][HBINS] u32   @ 0         (131072)
// box  : float4 [BB*NN]    @ 131072    (6451200)
// score: float  [BB*NN]    @ 6582272   (1612800)
// cls  : u32    [BB*NN]    @ 8195072   (1612800)  total ~9.8MB
static const size_t OFF_BOX = 131072;
static const size_t OFF_SCR = 6582272;
static const size_t OFF_CLS = 8195072;

// One wave per block; stages 64 contiguous rows (5440 floats, 16B-aligned)
// through LDS with coalesced float4 loads, then each lane processes one row.
__global__ __launch_bounds__(64) void k_pre(const float* __restrict__ pred,
                                            float4* __restrict__ boxArr,
                                            float* __restrict__ scoreArr,
                                            unsigned* __restrict__ clsArr,
                                            unsigned* __restrict__ hist) {
    __shared__ float tile[64 * 85];
    int lane = threadIdx.x;
    int rowbase = blockIdx.x * 64;
    const float4* src = (const float4*)(pred + (size_t)rowbase * ROW);
    float4 r[21];
#pragma unroll
    for (int it = 0; it < 21; ++it) r[it] = src[it * 64 + lane];
    float tailv = pred[(size_t)rowbase * ROW + 5376 + lane];
#pragma unroll
    for (int it = 0; it < 21; ++it) *(float4*)&tile[(it * 64 + lane) * 4] = r[it];
    tile[5376 + lane] = tailv;
    __syncthreads();

    const float* row = &tile[lane * ROW];  // stride 85: 2-way LDS aliasing (free)
    float cx = row[0], cy = row[1], w = row[2], h = row[3], obj = row[4];
    float best = __fmul_rn(row[5], obj);
    int bj = 0;
#pragma unroll 4
    for (int c = 1; c < NCLS; ++c) {
        float v = __fmul_rn(row[5 + c], obj);
        if (v > best) { best = v; bj = c; }
    }
    float hw = __fmul_rn(w, 0.5f), hh = __fmul_rn(h, 0.5f);
    float4 bx;
    bx.x = __fsub_rn(cx, hw);
    bx.y = __fsub_rn(cy, hh);
    bx.z = __fadd_rn(cx, hw);
    bx.w = __fadd_rn(cy, hh);
    bool valid = (obj > CONF_T) && (best > CONF_T);
    float score = valid ? best : -1.0f;

    int i = rowbase + lane;
    boxArr[i] = bx;
    scoreArr[i] = score;
    clsArr[i] = (unsigned)bj;
    if (score > 0.0f) {
        unsigned key = (__float_as_uint(score) - 0x3E800000u) >> 13;
        if (key > HBINS - 1) key = HBINS - 1;
        atomicAdd(&hist[(i / NN) * HBINS + key], 1u);
    }
}

// One block per image: threshold (LDS suffix scan) -> compact -> bitonic 512
// -> batched-64 ballot NMS -> outputs. All exact w.r.t. reference ordering.
__global__ __launch_bounds__(256) void k_nms(const float4* __restrict__ boxArr,
                                             const unsigned* __restrict__ clsArr,
                                             const float* __restrict__ logits,
                                             const float* __restrict__ scoreArr,
                                             const unsigned* __restrict__ hist,
                                             float* __restrict__ out) {
    __shared__ unsigned h[HBINS];
    __shared__ unsigned csum[257];
    __shared__ float  ls[CAP2];
    __shared__ int    li[CAP2];
    __shared__ float4 cbox[CAP2];
    __shared__ float4 kbox[MAXDET];
    __shared__ int    rowsrc[MAXDET];
    __shared__ float  rowscore[MAXDET];
    __shared__ int    s_thr, s_cnt, s_kept;

    int b = blockIdx.x, tid = threadIdx.x;

    for (int k = tid; k < HBINS; k += 256) h[k] = hist[b * HBINS + k];
    if (tid == 0) { s_cnt = 0; s_thr = 0; }
    __syncthreads();

    // per-thread chunk sum (8 bins each), then Hillis-Steele suffix scan
    unsigned cs = 0;
#pragma unroll
    for (int t = 0; t < 8; ++t) cs += h[tid * 8 + t];
    csum[tid] = cs;
    __syncthreads();
    for (int off = 1; off < 256; off <<= 1) {
        unsigned v = csum[tid];
        unsigned add = (tid + off < 256) ? csum[tid + off] : 0u;
        __syncthreads();
        csum[tid] = v + add;
        __syncthreads();
    }
    // t = max{k : S(k) >= TGT}, S = suffix count (matches serial reference scan)
    {
        unsigned Sc = csum[tid];
        unsigned Sn = (tid < 255) ? csum[tid + 1] : 0u;
        if (Sc >= TGT && (tid == 255 || Sn < TGT)) {
            unsigned cum = Sn;
            int t = tid * 8;
            for (int k = tid * 8 + 7; k >= tid * 8; --k) {
                cum += h[k];
                if (cum >= TGT) { t = k; break; }
            }
            s_thr = t;
        }
    }
    __syncthreads();
    unsigned thr = (unsigned)s_thr;

    // compact candidates above threshold bin into LDS
    for (int n = tid; n < NN; n += 256) {
        float s = scoreArr[(size_t)b * NN + n];
        if (s > 0.0f) {
            unsigned key = (__float_as_uint(s) - 0x3E800000u) >> 13;
            if (key > HBINS - 1) key = HBINS - 1;
            if (key >= thr) {
                int pos = atomicAdd(&s_cnt, 1);
                if (pos < CAP2) { ls[pos] = s; li[pos] = n; }
            }
        }
    }
    __syncthreads();
    int c = min(s_cnt, CAP2);
    for (int p = tid; p < CAP2; p += 256)
        if (p >= c) { ls[p] = -1e30f; li[p] = 0x7fffffff; }
    __syncthreads();

    // bitonic sort 512, descending (score, then ascending idx) — exact total order
    for (int k = 2; k <= CAP2; k <<= 1) {
        for (int j = k >> 1; j > 0; j >>= 1) {
            for (int i = tid; i < CAP2; i += 256) {
                int ixj = i ^ j;
                if (ixj > i) {
                    float s1 = ls[i], s2 = ls[ixj];
                    int i1 = li[i], i2 = li[ixj];
                    bool before = (s1 > s2) || (s1 == s2 && i1 < i2);
                    bool sw = ((i & k) == 0) ? !before : before;
                    if (sw) { ls[i] = s2; ls[ixj] = s1; li[i] = i2; li[ixj] = i1; }
                }
            }
            __syncthreads();
        }
    }

    // gather class-offset boxes for sorted candidates
    for (int p = tid; p < c; p += 256) {
        int n = li[p];
        float4 bb = boxArr[(size_t)b * NN + n];
        float off = __fmul_rn((float)clsArr[(size_t)b * NN + n], 4096.0f);
        bb.x = __fadd_rn(bb.x, off);
        bb.y = __fadd_rn(bb.y, off);
        bb.z = __fadd_rn(bb.z, off);
        bb.w = __fadd_rn(bb.w, off);
        cbox[p] = bb;
    }
    __syncthreads();

    // wave-0 batched greedy NMS: 64 candidates per chunk; broadcast kept-box
    // test in parallel, ballot-resolved in-chunk suppression. Exact greedy order.
    if (tid < 64) {
        int lane = tid;
        int kept = 0;
        for (int p0 = 0; p0 < c && kept < MAXDET; p0 += 64) {
            int i = p0 + lane;
            float4 cb = (i < c) ? cbox[i] : make_float4(0.f, 0.f, 0.f, 0.f);
            float a2 = __fmul_rn(__fsub_rn(cb.z, cb.x), __fsub_rn(cb.w, cb.y));
            bool sup = (i >= c);
            for (int k = 0; k < kept; ++k) {
                float4 kb = kbox[k];  // same-address broadcast read
                float ltx = fmaxf(kb.x, cb.x), lty = fmaxf(kb.y, cb.y);
                float rbx = fminf(kb.z, cb.z), rby = fminf(kb.w, cb.w);
                float ww = fmaxf(__fsub_rn(rbx, ltx), 0.0f);
                float hh = fmaxf(__fsub_rn(rby, lty), 0.0f);
                float inter = __fmul_rn(ww, hh);
                float a1 = __fmul_rn(__fsub_rn(kb.z, kb.x), __fsub_rn(kb.w, kb.y));
                float denom = __fadd_rn(__fsub_rn(__fadd_rn(a1, a2), inter), 1e-9f);
                sup = sup || (inter / denom > IOU_T);
            }
            unsigned long long m = __ballot(sup);
            int lim = min(64, c - p0);
            for (int j = 0; j < lim; ++j) {
                if (!((m >> j) & 1ULL)) {
                    if (lane == j) { kbox[kept] = cb; rowsrc[kept] = li[i]; rowscore[kept] = ls[i]; }
                    kept++;
                    if (kept >= MAXDET) break;
                    float jx = __shfl(cb.x, j), jy = __shfl(cb.y, j);
                    float jz = __shfl(cb.z, j), jw = __shfl(cb.w, j);
                    float aj = __shfl(a2, j);
                    if (lane > j) {
                        float ltx = fmaxf(jx, cb.x), lty = fmaxf(jy, cb.y);
                        float rbx = fminf(jz, cb.z), rby = fminf(jw, cb.w);
                        float ww = fmaxf(__fsub_rn(rbx, ltx), 0.0f);
                        float hh = fmaxf(__fsub_rn(rby, lty), 0.0f);
                        float inter = __fmul_rn(ww, hh);
                        float denom = __fadd_rn(__fsub_rn(__fadd_rn(aj, a2), inter), 1e-9f);
                        if (inter / denom > IOU_T) sup = true;
                    }
                    m |= __ballot(sup);
                }
            }
        }
        if (lane == 0) s_kept = kept;
    }
    __syncthreads();
    int kept = s_kept;

    // outputs — every element written every launch (d_out is poisoned)
    float* dets = out;
    float* lg   = out + (size_t)BB * MAXDET * 6;
    float* kp   = lg  + (size_t)BB * MAXDET * NCLS;

    for (int i = tid; i < MAXDET * 6; i += 256) {
        int t = i / 6, col = i - t * 6;
        float v = 0.0f;
        if (t < kept) {
            int n = rowsrc[t];
            if (col < 4) {
                const float* bp = (const float*)&boxArr[(size_t)b * NN + n];
                v = bp[col];
            } else if (col == 4) {
                v = rowscore[t];
            } else {
                v = (float)clsArr[(size_t)b * NN + n];
            }
        }
        dets[(size_t)b * MAXDET * 6 + i] = v;
    }
    for (int i = tid; i < MAXDET; i += 256)
        kp[b * MAXDET + i] = (i < kept) ? 1.0f : 0.0f;
    for (int i = tid; i < MAXDET * NCLS; i += 256) {
        int t = i / NCLS, col = i - t * NCLS;
        float v = 0.0f;
        if (t < kept) v = logits[((size_t)b * NN + rowsrc[t]) * NCLS + col];
        lg[(size_t)b * MAXDET * NCLS + i] = v;
    }
}

extern "C" void kernel_launch(void* const* d_in, const int* in_sizes, int n_in,
                              void* d_out, int out_size, void* d_ws, size_t ws_size,
                              hipStream_t stream) {
    const float* pred   = (const float*)d_in[0];
    const float* logits = (const float*)d_in[1];
    float* out = (float*)d_out;
    char* ws = (char*)d_ws;

    unsigned* hist = (unsigned*)ws;
    float4*   box  = (float4*)(ws + OFF_BOX);
    float*    scr  = (float*)(ws + OFF_SCR);
    unsigned* cls  = (unsigned*)(ws + OFF_CLS);

    hipMemsetAsync(ws, 0, BB * HBINS * sizeof(unsigned), stream);

    int blocks = (BB * NN) / 64;  // 6300, exact
    k_pre<<<blocks, 64, 0, stream>>>(pred, box, scr, cls, hist);
    k_nms<<<BB, 256, 0, stream>>>(box, cls, logits, scr, hist, out);
}

// Round 3
// 353.265 us; speedup vs baseline: 2.4139x; 1.3986x over previous
//
#include <hip/hip_runtime.h>
#include <cstdint>

#define BB 16
#define NN 25200
#define NCLS 80
#define ROW 85
#define MAXDET 300
#define HBINS 2048
#define CAP2 512
#define TGT 448
#define CONF_T 0.25f
#define IOU_T 0.45f
#define NT 1024

// ---------------- workspace layout (bytes) ----------------
// box  : float4 [BB*NN] @ 0         (6451200)
// score: float  [BB*NN] @ 6451200   (1612800)
// cls  : u32    [BB*NN] @ 8064000   (1612800)   total ~9.7MB
static const size_t OFF_SCR = 6451200;
static const size_t OFF_CLS = 8064000;

// Pure streaming: stage 64 rows through LDS with coalesced float4 loads,
// per-lane conf/argmax/xyxy, write aux arrays. NO atomics (r2's global-hist
// atomics are the prime suspect for the ~240us plateau).
__global__ __launch_bounds__(64) void k_pre(const float* __restrict__ pred,
                                            float4* __restrict__ boxArr,
                                            float* __restrict__ scoreArr,
                                            unsigned* __restrict__ clsArr) {
    __shared__ float tile[64 * 85];
    int lane = threadIdx.x;
    int rowbase = blockIdx.x * 64;
    const float4* src = (const float4*)(pred + (size_t)rowbase * ROW);
    float4 r[21];
#pragma unroll
    for (int it = 0; it < 21; ++it) r[it] = src[it * 64 + lane];
    float tailv = pred[(size_t)rowbase * ROW + 5376 + lane];
#pragma unroll
    for (int it = 0; it < 21; ++it) *(float4*)&tile[(it * 64 + lane) * 4] = r[it];
    tile[5376 + lane] = tailv;
    __syncthreads();

    const float* row = &tile[lane * ROW];  // stride 85: 2-way aliasing (free)
    float cx = row[0], cy = row[1], w = row[2], h = row[3], obj = row[4];
    float best = __fmul_rn(row[5], obj);
    int bj = 0;
#pragma unroll 4
    for (int c = 1; c < NCLS; ++c) {
        float v = __fmul_rn(row[5 + c], obj);
        if (v > best) { best = v; bj = c; }
    }
    float hw = __fmul_rn(w, 0.5f), hh = __fmul_rn(h, 0.5f);
    float4 bx;
    bx.x = __fsub_rn(cx, hw);
    bx.y = __fsub_rn(cy, hh);
    bx.z = __fadd_rn(cx, hw);
    bx.w = __fadd_rn(cy, hh);
    bool valid = (obj > CONF_T) && (best > CONF_T);

    int i = rowbase + lane;
    boxArr[i] = bx;
    scoreArr[i] = valid ? best : -1.0f;
    clsArr[i] = (unsigned)bj;
}

// One block per image, 1024 threads. Phases:
//  hist(LDS atomics, scores reg-cached) -> threshold scan -> compact(from regs)
//  -> bitonic 512 -> gather boxes -> pairwise suppression bitmask (parallel)
//  -> bit-OR greedy resolve (exact greedy order) -> rank-scatter -> outputs.
__global__ __launch_bounds__(NT) void k_nms(const float4* __restrict__ boxArr,
                                            const unsigned* __restrict__ clsArr,
                                            const float* __restrict__ logits,
                                            const float* __restrict__ scoreArr,
                                            float* __restrict__ out) {
    // ---- LDS overlay map (62.3KB) ----
    __shared__ __align__(16) char smem[63792];
    float*    ls    = (float*)smem;                       //  512 f32
    int*      li    = (int*)(smem + 2048);                //  512 i32
    int*      flags = (int*)(smem + 4096);                //  [0]=cnt [1]=thr [2]=kept
    unsigned* hist  = (unsigned*)(smem + 4112);           // 2048 u32  (phase A)
    unsigned* csum  = (unsigned*)(smem + 12304);          //  257 u32  (phase A)
    unsigned long long* mask = (unsigned long long*)(smem + 4112);  // 512x8 u64 (phase B, overlays hist)
    float4*   cbox  = (float4*)(smem + 36880);            //  512 (class-offset boxes)
    float4*   rawbox= (float4*)(smem + 45072);            //  512
    unsigned* ccls  = (unsigned*)(smem + 53264);          //  512
    float4*   rowbox= (float4*)(smem + 55312);            //  300
    float*    rowscore = (float*)(smem + 60112);          //  300
    unsigned* rowcls   = (unsigned*)(smem + 61312);       //  300
    unsigned long long* keepm = (unsigned long long*)(smem + 62512); // 8 u64
    unsigned* rowsrc   = (unsigned*)(smem + 62576);       //  300

    int b = blockIdx.x, tid = threadIdx.x;

    // phase 0: init
    for (int k = tid; k < HBINS; k += NT) hist[k] = 0u;
    if (tid == 0) { flags[0] = 0; flags[1] = 0; }
    __syncthreads();

    // phase 1: single global pass — cache scores in registers, build LDS hist
    float sreg[25];
#pragma unroll
    for (int t = 0; t < 25; ++t) {
        int n = tid + t * NT;
        float s = (n < NN) ? scoreArr[(size_t)b * NN + n] : -1.0f;
        sreg[t] = s;
        if (s > 0.0f) {
            unsigned key = (__float_as_uint(s) - 0x3E800000u) >> 13;
            if (key > HBINS - 1) key = HBINS - 1;
            atomicAdd(&hist[key], 1u);
        }
    }
    __syncthreads();

    // phase 2: suffix scan -> threshold bin (same verified logic as r2)
    if (tid < 256) {
        unsigned cs = 0;
#pragma unroll
        for (int t = 0; t < 8; ++t) cs += hist[tid * 8 + t];
        csum[tid] = cs;
    }
    __syncthreads();
    for (int off = 1; off < 256; off <<= 1) {
        unsigned v = 0, add = 0;
        if (tid < 256) {
            v = csum[tid];
            add = (tid + off < 256) ? csum[tid + off] : 0u;
        }
        __syncthreads();
        if (tid < 256) csum[tid] = v + add;
        __syncthreads();
    }
    if (tid < 256) {
        unsigned Sc = csum[tid];
        unsigned Sn = (tid < 255) ? csum[tid + 1] : 0u;
        if (Sc >= TGT && (tid == 255 || Sn < TGT)) {
            unsigned cum = Sn;
            int t = tid * 8;
            for (int k = tid * 8 + 7; k >= tid * 8; --k) {
                cum += hist[k];
                if (cum >= TGT) { t = k; break; }
            }
            flags[1] = t;
        }
    }
    __syncthreads();
    unsigned thr = (unsigned)flags[1];

    // phase 3: compact from registers (no global re-read)
#pragma unroll
    for (int t = 0; t < 25; ++t) {
        float s = sreg[t];
        if (s > 0.0f) {
            unsigned key = (__float_as_uint(s) - 0x3E800000u) >> 13;
            if (key > HBINS - 1) key = HBINS - 1;
            if (key >= thr) {
                int pos = atomicAdd(&flags[0], 1);
                if (pos < CAP2) { ls[pos] = s; li[pos] = tid + t * NT; }
            }
        }
    }
    __syncthreads();
    int c = min(flags[0], CAP2);
    for (int p = tid; p < CAP2; p += NT)
        if (p >= c) { ls[p] = -1e30f; li[p] = 0x7fffffff; }
    __syncthreads();

    // phase 4: bitonic sort 512 desc by (score, then asc idx) — exact total order
    for (int k = 2; k <= CAP2; k <<= 1) {
        for (int j = k >> 1; j > 0; j >>= 1) {
            for (int i = tid; i < CAP2; i += NT) {
                int ixj = i ^ j;
                if (ixj > i) {
                    float s1 = ls[i], s2 = ls[ixj];
                    int i1 = li[i], i2 = li[ixj];
                    bool before = (s1 > s2) || (s1 == s2 && i1 < i2);
                    bool sw = ((i & k) == 0) ? !before : before;
                    if (sw) { ls[i] = s2; ls[ixj] = s1; li[i] = i2; li[ixj] = i1; }
                }
            }
            __syncthreads();
        }
    }

    // phase 5: gather raw + class-offset boxes (zero-fill tail for safe IoU)
    for (int p = tid; p < CAP2; p += NT) {
        if (p < c) {
            int n = li[p];
            float4 bb = boxArr[(size_t)b * NN + n];
            unsigned cl = clsArr[(size_t)b * NN + n];
            rawbox[p] = bb;
            float off = __fmul_rn((float)cl, 4096.0f);
            float4 ob;
            ob.x = __fadd_rn(bb.x, off);
            ob.y = __fadd_rn(bb.y, off);
            ob.z = __fadd_rn(bb.z, off);
            ob.w = __fadd_rn(bb.w, off);
            cbox[p] = ob;
            ccls[p] = cl;
        } else {
            rawbox[p] = make_float4(0.f, 0.f, 0.f, 0.f);
            cbox[p]   = make_float4(0.f, 0.f, 0.f, 0.f);
            ccls[p] = 0u;
        }
    }
    __syncthreads();

    // phase 6: pairwise suppression bitmask. Task (i,w): bits for j in [64w,64w+64).
    // Cross-class pairs: offset boxes disjoint -> inter==0 -> cheap skip of divide.
    for (int task = tid; task < CAP2 * 8; task += NT) {
        int i = task & (CAP2 - 1);
        int w = task >> 9;
        unsigned long long m = 0ULL;
        if (i < c) {
            float4 ci = cbox[i];
            float a1 = __fmul_rn(__fsub_rn(ci.z, ci.x), __fsub_rn(ci.w, ci.y));
#pragma unroll 4
            for (int jj = 0; jj < 64; ++jj) {
                float4 cj = cbox[w * 64 + jj];  // same-address broadcast
                float ltx = fmaxf(ci.x, cj.x), lty = fmaxf(ci.y, cj.y);
                float rbx = fminf(ci.z, cj.z), rby = fminf(ci.w, cj.w);
                float ww = fmaxf(__fsub_rn(rbx, ltx), 0.0f);
                float hh = fmaxf(__fsub_rn(rby, lty), 0.0f);
                float inter = __fmul_rn(ww, hh);
                if (inter > 0.0f) {
                    float a2 = __fmul_rn(__fsub_rn(cj.z, cj.x), __fsub_rn(cj.w, cj.y));
                    float denom = __fadd_rn(__fsub_rn(__fadd_rn(a1, a2), inter), 1e-9f);
                    if (inter / denom > IOU_T) m |= (1ULL << jj);
                }
            }
        }
        mask[i * 8 + w] = m;
    }
    __syncthreads();

    // phase 7: greedy bit-OR resolve on wave 0 (all lanes redundant; broadcast reads).
    // removed |= mask[row] on each keep — exactly greedy argmax NMS in sorted order.
    if (tid < 64) {
        unsigned long long rem[8] = {0,0,0,0,0,0,0,0};
        unsigned long long kp[8]  = {0,0,0,0,0,0,0,0};
        int kept = 0;
        for (int p = 0; p < c && kept < MAXDET; ++p) {
            int w = p >> 6, bit = p & 63;
            if (!((rem[w] >> bit) & 1ULL)) {
                kp[w] |= (1ULL << bit);
                kept++;
#pragma unroll
                for (int q = 0; q < 8; ++q) rem[q] |= mask[p * 8 + q];
            }
        }
        if (tid == 0) {
            flags[2] = kept;
#pragma unroll
            for (int q = 0; q < 8; ++q) keepm[q] = kp[q];
        }
    }
    __syncthreads();
    int kept = flags[2];

    // phase 8: rank-scatter kept rows into dense [0,kept)
    {
        unsigned long long km[8];
#pragma unroll
        for (int q = 0; q < 8; ++q) km[q] = keepm[q];
        for (int p = tid; p < c; p += NT) {
            int w = p >> 6, bit = p & 63;
            if ((km[w] >> bit) & 1ULL) {
                int rank = __popcll(km[w] & ((1ULL << bit) - 1ULL));
#pragma unroll
                for (int q = 0; q < 8; ++q) rank += (q < w) ? __popcll(km[q]) : 0;
                if (rank < MAXDET) {
                    rowbox[rank] = rawbox[p];
                    rowscore[rank] = ls[p];
                    rowcls[rank] = ccls[p];
                    rowsrc[rank] = (unsigned)li[p];
                }
            }
        }
    }
    __syncthreads();

    // phase 9: outputs — every element written every launch (d_out poisoned)
    float* dets = out;
    float* lg   = out + (size_t)BB * MAXDET * 6;
    float* kpo  = lg  + (size_t)BB * MAXDET * NCLS;

    for (int i = tid; i < MAXDET * 6; i += NT) {
        int t = i / 6, col = i - t * 6;
        float v = 0.0f;
        if (t < kept) {
            if (col < 4)      v = ((const float*)&rowbox[t])[col];
            else if (col == 4) v = rowscore[t];
            else               v = (float)rowcls[t];
        }
        dets[(size_t)b * MAXDET * 6 + i] = v;
    }
    for (int i = tid; i < MAXDET; i += NT)
        kpo[b * MAXDET + i] = (i < kept) ? 1.0f : 0.0f;
    for (int i = tid; i < MAXDET * NCLS; i += NT) {
        int t = i / NCLS, col = i - t * NCLS;
        float v = 0.0f;
        if (t < kept) v = logits[((size_t)b * NN + rowsrc[t]) * NCLS + col];
        lg[(size_t)b * MAXDET * NCLS + i] = v;
    }
}

extern "C" void kernel_launch(void* const* d_in, const int* in_sizes, int n_in,
                              void* d_out, int out_size, void* d_ws, size_t ws_size,
                              hipStream_t stream) {
    const float* pred   = (const float*)d_in[0];
    const float* logits = (const float*)d_in[1];
    float* out = (float*)d_out;
    char* ws = (char*)d_ws;

    float4*   box = (float4*)ws;
    float*    scr = (float*)(ws + OFF_SCR);
    unsigned* cls = (unsigned*)(ws + OFF_CLS);

    int blocks = (BB * NN) / 64;  // 6300, exact
    k_pre<<<blocks, 64, 0, stream>>>(pred, box, scr, cls);
    k_nms<<<BB, NT, 0, stream>>>(box, cls, logits, scr, out);
}